// Round 6
// baseline (1090.820 us; speedup 1.0000x reference)
//
#include <hip/hip_runtime.h>
#include <stdint.h>

// Problem constants: B=8, N=4096, C=768, G=16, D=48
// qkv GEMM: M=32768, N=2304, K=768 ; proj GEMM: M=32768, N=768, K=768

using short8 = __attribute__((__ext_vector_type__(8))) short;
using f32x4  = __attribute__((__ext_vector_type__(4))) float;

typedef const void __attribute__((address_space(1))) gv_t;
typedef void __attribute__((address_space(3))) lv_t;

__device__ __forceinline__ void gll16(const void* g, void* l) {
  __builtin_amdgcn_global_load_lds((gv_t*)g, (lv_t*)l, 16, 0, 0);
}

__device__ __forceinline__ uint16_t f2b(float f) {
  uint32_t x = __float_as_uint(f);
  uint32_t r = (x + 0x7fffu + ((x >> 16) & 1u)) >> 16;  // RNE
  return (uint16_t)r;
}
__device__ __forceinline__ float b2f(uint16_t u) {
  return __uint_as_float(((uint32_t)u) << 16);
}

// ---------------- cast / transpose helpers ----------------

__global__ __launch_bounds__(256) void cast_x_kernel(const float* __restrict__ x,
                                                     uint16_t* __restrict__ xb, int n4) {
  int i = blockIdx.x * 256 + threadIdx.x;
  if (i >= n4) return;
  f32x4 v = ((const f32x4*)x)[i];
  union { uint16_t u[4]; uint64_t q; } o;
  o.u[0] = f2b(v[0]); o.u[1] = f2b(v[1]); o.u[2] = f2b(v[2]); o.u[3] = f2b(v[3]);
  ((uint64_t*)xb)[i] = o.q;
}

// wt[n*K + k] = (bf16) w[k*N + n]
__global__ __launch_bounds__(256) void transpose_cast_kernel(const float* __restrict__ w,
                                                             uint16_t* __restrict__ wt,
                                                             int K, int N) {
  int i = blockIdx.x * 256 + threadIdx.x;
  if (i >= N * K) return;
  int n = i / K, k = i - n * K;
  wt[i] = f2b(w[(size_t)k * N + n]);
}

// ---------------- pipelined 256x256 GEMM, BK=32, ring-4 LDS, depth-3 prefetch ------
// A [M][768] bf16 row-major; Bt [N][768] bf16 row-major (weights transposed).
// 512 threads / 8 waves (2M x 4N), wave tile 128x64, acc[8][4] (128 VGPR).
// Round-6 fix: __launch_bounds__(512, 2) meant min 2 BLOCKS/CU -> 4 waves/EU -> 128-VGPR
// cap -> acc spilled (rounds 3-4: 2.8 GB scratch WRITE). (512, 1) gives >=256 VGPR under
// either launch-bounds reading; round-5's 256-thr build confirmed ~236 VGPR fits spill-free.
// LDS swizzle (both sides): phys 16B-slot = logical ^ ((row>>1)&3) -> 2-way banks = free.
// Counted vmcnt(8): 12 loads in flight (3 stages x 4), never drained to 0 until tail.

template<int MODE>
__global__ __launch_bounds__(512, 1) void gemm256_kernel(
    const uint16_t* __restrict__ A, const uint16_t* __restrict__ Bt,
    const float* __restrict__ bias,
    uint16_t* __restrict__ Qb, uint16_t* __restrict__ Kb,
    uint16_t* __restrict__ Vb, float* __restrict__ outf) {
  constexpr int NT = 24;                       // 768 / 32
  constexpr int NB = (MODE == 0) ? 9 : 3;      // 256-col blocks
  constexpr int NWG = 128 * NB;                // 128 row-blocks of 256
  constexpr int CPX = NWG / 8;
  __shared__ uint16_t lds[4 * 16384];          // 128 KiB: slot s: A @ s*16384, B @ +8192

  const int tid  = threadIdx.x;
  const int lane = tid & 63, w = tid >> 6;
  const int wm = w >> 2, wn = w & 3;
  const int lrow = lane & 15, kb = lane >> 4;

  int wg = (int)blockIdx.x;
  wg = (wg & 7) * CPX + (wg >> 3);             // bijective XCD swizzle (NWG%8==0)
  const int mblk = wg / NB, nblk = wg % NB;    // nblk fastest: A-panel L2 reuse
  const int m0 = mblk * 256, n0 = nblk * 256;
  const bool sw = (MODE == 0) && (n0 < 1536);  // Q/K blocks: swapped-operand MFMA

  // staging: wave w stages A rows [w*32,+32) and B rows ditto; lane l covers row
  // chunk + (l>>2); global 16B-chunk inverse-swizzled so linear LDS + swz read = id.
  const int grow  = lane >> 2;
  const int gslot = ((lane & 3) ^ ((lane >> 3) & 3)) << 3;
  const size_t arow0 = (size_t)(m0 + w * 32 + grow) * 768 + gslot;
  const size_t brow0 = (size_t)(n0 + w * 32 + grow) * 768 + gslot;

  auto stage = [&](int ts) {
    const int sl = ts & 3;
    const size_t ko = (size_t)ts * 32;
    uint16_t* la = lds + sl * 16384 + w * 1024;   // wave-uniform LDS dest
    uint16_t* lb = la + 8192;
    gll16(A  + arow0 + ko,            la);
    gll16(A  + arow0 + ko + 16 * 768, la + 512);
    gll16(Bt + brow0 + ko,            lb);
    gll16(Bt + brow0 + ko + 16 * 768, lb + 512);
  };

  const int xslot = (kb ^ ((lrow >> 1) & 3)) << 3;  // swizzled read slot (elements)

  f32x4 acc[8][4] = {};

  stage(0); stage(1); stage(2);
  asm volatile("s_waitcnt vmcnt(8)" ::: "memory");
  __builtin_amdgcn_s_barrier();
  __builtin_amdgcn_sched_barrier(0);

  for (int t = 0; t < NT; ++t) {
    if (t + 3 < NT) stage(t + 3);
    const uint16_t* sa = lds + (t & 3) * 16384;
    const uint16_t* sb = sa + 8192;
    short8 av[8], bv4[4];
#pragma unroll
    for (int mf = 0; mf < 8; ++mf)
      av[mf] = *(const short8*)(sa + (wm * 128 + mf * 16 + lrow) * 32 + xslot);
#pragma unroll
    for (int nf = 0; nf < 4; ++nf)
      bv4[nf] = *(const short8*)(sb + (wn * 64 + nf * 16 + lrow) * 32 + xslot);
    __builtin_amdgcn_s_setprio(1);
    if (sw) {
#pragma unroll
      for (int mf = 0; mf < 8; ++mf)
#pragma unroll
        for (int nf = 0; nf < 4; ++nf)
          acc[mf][nf] = __builtin_amdgcn_mfma_f32_16x16x32_bf16(bv4[nf], av[mf], acc[mf][nf], 0, 0, 0);
    } else {
#pragma unroll
      for (int mf = 0; mf < 8; ++mf)
#pragma unroll
        for (int nf = 0; nf < 4; ++nf)
          acc[mf][nf] = __builtin_amdgcn_mfma_f32_16x16x32_bf16(av[mf], bv4[nf], acc[mf][nf], 0, 0, 0);
    }
    __builtin_amdgcn_s_setprio(0);
    if (t < NT - 1) {
      if (t <= NT - 4)      asm volatile("s_waitcnt vmcnt(8)" ::: "memory");
      else if (t == NT - 3) asm volatile("s_waitcnt vmcnt(4)" ::: "memory");
      else                  asm volatile("s_waitcnt vmcnt(0)" ::: "memory");
      __builtin_amdgcn_s_barrier();
      __builtin_amdgcn_sched_barrier(0);
    }
  }

  const float qscale = 0.015625f;  // 4096^-0.5
  if (MODE == 0) {
    const int which = n0 / 768;
    if (which < 2) {
      // swapped-operand MFMA -> frag col (lrow) = token, frag row (kb*4+r) = channel
      uint16_t* dst = (which == 0) ? Qb : Kb;
      const float sc = (which == 0) ? qscale : 1.0f;
#pragma unroll
      for (int mf = 0; mf < 8; ++mf) {
        const int token = m0 + wm * 128 + mf * 16 + lrow;
        const int b = token >> 12, nn = token & 4095;
#pragma unroll
        for (int nf = 0; nf < 4; ++nf) {
          const int colb = n0 + wn * 64 + nf * 16 + kb * 4;
#pragma unroll
          for (int r = 0; r < 4; ++r) {
            const int chan = colb + r - which * 768;
            const int g = chan / 48, d = chan - g * 48;
            dst[(((size_t)b * 16 + g) * 48 + d) * 4096 + nn] =
                f2b((acc[mf][nf][r] + bias[colb + r]) * sc);
          }
        }
      }
    } else {
#pragma unroll
      for (int mf = 0; mf < 8; ++mf) {
        const int rowb = m0 + wm * 128 + mf * 16 + kb * 4;
#pragma unroll
        for (int nf = 0; nf < 4; ++nf) {
          const int col = n0 + wn * 64 + nf * 16 + lrow;
          const int c = col - 1536, g = c / 48, d = c - g * 48;
          const float bb = bias[col];
#pragma unroll
          for (int r = 0; r < 4; ++r) {
            const int row = rowb + r;
            const int b = row >> 12, nn = row & 4095;
            Vb[(((size_t)b * 16 + g) * 4096 + nn) * 48 + d] = f2b(acc[mf][nf][r] + bb);
          }
        }
      }
    }
  } else {
#pragma unroll
    for (int mf = 0; mf < 8; ++mf) {
      const int rowb = m0 + wm * 128 + mf * 16 + kb * 4;
#pragma unroll
      for (int nf = 0; nf < 4; ++nf) {
        const int col = n0 + wn * 64 + nf * 16 + lrow;
        const float bb = bias[col];
#pragma unroll
        for (int r = 0; r < 4; ++r)
          outf[(size_t)(rowb + r) * 768 + col] = acc[mf][nf][r] + bb;
      }
    }
  }
}

// ---------------- logits via MFMA over token-K ----------------
// Qt,Kt: [bg][48][4096] bf16.  part[ch][bg][48][48] f32, ch in 0..7 (512 tokens each)

__global__ __launch_bounds__(256) void logits_mfma_kernel(
    const uint16_t* __restrict__ Qt, const uint16_t* __restrict__ Kt,
    float* __restrict__ part) {
  const int bg = blockIdx.x;     // 0..127
  const int ch = blockIdx.y;     // 0..7
  const int tid = threadIdx.x;
  const int lane = tid & 63, w = tid >> 6;
  const int lrow = lane & 15, kb = lane >> 4;

  const size_t qbase = (size_t)bg * 48 * 4096;
  const int tok0 = ch * 512 + w * 128;

  f32x4 acc[3][3] = {};
#pragma unroll
  for (int s = 0; s < 4; ++s) {
    const int tok = tok0 + s * 32 + kb * 8;
    short8 av[3], bvv[3];
#pragma unroll
    for (int dm = 0; dm < 3; ++dm) {
      av[dm]  = *(const short8*)(Qt + qbase + (size_t)(dm * 16 + lrow) * 4096 + tok);
      bvv[dm] = *(const short8*)(Kt + qbase + (size_t)(dm * 16 + lrow) * 4096 + tok);
    }
#pragma unroll
    for (int dm = 0; dm < 3; ++dm)
#pragma unroll
      for (int em = 0; em < 3; ++em)
        acc[dm][em] = __builtin_amdgcn_mfma_f32_16x16x32_bf16(av[dm], bvv[em], acc[dm][em], 0, 0, 0);
  }

  __shared__ float red[4][2304];
#pragma unroll
  for (int dm = 0; dm < 3; ++dm)
#pragma unroll
    for (int em = 0; em < 3; ++em)
#pragma unroll
      for (int r = 0; r < 4; ++r) {
        const int d = dm * 16 + kb * 4 + r;
        const int e = em * 16 + lrow;
        red[w][d * 48 + e] = acc[dm][em][r];
      }
  __syncthreads();
  float* dst = part + ((size_t)ch * 128 + bg) * 2304;
  for (int i = tid; i < 2304; i += 256)
    dst[i] = red[0][i] + red[1][i] + red[2][i] + red[3][i];
}

// ---------------- reduce partials + softmax over e ----------------

__global__ __launch_bounds__(256) void softmax_kernel(const float* __restrict__ part,
                                                      float* __restrict__ attn) {
  const int bg = blockIdx.x;
  const int tid = threadIdx.x;
  __shared__ float l[2304];
  for (int p = tid; p < 2304; p += 256) {
    float s = 0.f;
    for (int chk = 0; chk < 8; ++chk) s += part[((size_t)chk * 128 + bg) * 2304 + p];
    l[p] = s;
  }
  __syncthreads();
  if (tid < 48) {
    const int d = tid;
    float m = -1e30f;
    for (int e = 0; e < 48; ++e) m = fmaxf(m, l[d * 48 + e]);
    float s = 0.f;
    for (int e = 0; e < 48; ++e) s += expf(l[d * 48 + e] - m);
    const float inv = 1.0f / s;
    for (int e = 0; e < 48; ++e)
      attn[(size_t)bg * 2304 + d * 48 + e] = expf(l[d * 48 + e] - m) * inv;
  }
}

// ---------------- block-diag: ao[b][n][g*48+d] = sum_e attn[bg][d][e] * v[bg][n][e] ------

__global__ __launch_bounds__(256) void blockdiag_kernel(const uint16_t* __restrict__ Vb,
                                                        const float* __restrict__ attn,
                                                        uint16_t* __restrict__ ao) {
  const int bg = blockIdx.x, ch = blockIdx.y;
  const int b = bg >> 4, g = bg & 15;
  const int tid = threadIdx.x;
  __shared__ uint16_t vs[128 * 64];
  __shared__ uint16_t as2[48 * 64];
  const size_t vbase = ((size_t)bg * 4096 + (size_t)ch * 128) * 48;
  for (int i = tid; i < 128 * 64; i += 256) {
    int n = i >> 6, e = i & 63;
    vs[i] = (e < 48) ? Vb[vbase + n * 48 + e] : (uint16_t)0;
  }
  const float* ab = attn + (size_t)bg * 2304;
  for (int i = tid; i < 48 * 64; i += 256) {
    int d = i >> 6, e = i & 63;
    as2[i] = (e < 48) ? f2b(ab[d * 48 + e]) : (uint16_t)0;
  }
  __syncthreads();
  const int lane = tid & 63, w = tid >> 6;
  const int lrow = lane & 15, kb = lane >> 4;
  f32x4 acc[2][3] = {};
#pragma unroll
  for (int ksb = 0; ksb < 2; ++ksb) {
    short8 a[2], bb[3];
#pragma unroll
    for (int i = 0; i < 2; ++i)
      a[i] = *(const short8*)(vs + (w * 32 + i * 16 + lrow) * 64 + ksb * 32 + kb * 8);
#pragma unroll
    for (int c = 0; c < 3; ++c)
      bb[c] = *(const short8*)(as2 + (c * 16 + lrow) * 64 + ksb * 32 + kb * 8);
#pragma unroll
    for (int i = 0; i < 2; ++i)
#pragma unroll
      for (int c = 0; c < 3; ++c)
        acc[i][c] = __builtin_amdgcn_mfma_f32_16x16x32_bf16(a[i], bb[c], acc[i][c], 0, 0, 0);
  }
#pragma unroll
  for (int i = 0; i < 2; ++i)
#pragma unroll
    for (int c = 0; c < 3; ++c)
#pragma unroll
      for (int r = 0; r < 4; ++r) {
        const int nl = w * 32 + i * 16 + kb * 4 + r;
        const int dcol = c * 16 + lrow;
        const size_t row = (size_t)b * 4096 + (size_t)ch * 128 + nl;
        ao[row * 768 + g * 48 + dcol] = f2b(acc[i][c][r]);
      }
}

// ---------------- launcher ----------------

extern "C" void kernel_launch(void* const* d_in, const int* in_sizes, int n_in,
                              void* d_out, int out_size, void* d_ws, size_t ws_size,
                              hipStream_t stream) {
  const float* x      = (const float*)d_in[0];
  const float* w_qkv  = (const float*)d_in[1];
  const float* b_qkv  = (const float*)d_in[2];
  const float* w_proj = (const float*)d_in[3];
  const float* b_proj = (const float*)d_in[4];
  float* out = (float*)d_out;

  char* w = (char*)d_ws;
  uint16_t* xb  = (uint16_t*)w; w += (size_t)32768 * 768 * 2;      // 50.3 MB (reused as ao)
  uint16_t* wqT = (uint16_t*)w; w += (size_t)2304 * 768 * 2;       // 3.5 MB
  uint16_t* wpT = (uint16_t*)w; w += (size_t)768 * 768 * 2;        // 1.2 MB
  uint16_t* Qt  = (uint16_t*)w; w += (size_t)128 * 48 * 4096 * 2;  // 50.3 MB
  uint16_t* Kt  = (uint16_t*)w; w += (size_t)128 * 48 * 4096 * 2;  // 50.3 MB
  uint16_t* Vb  = (uint16_t*)w; w += (size_t)128 * 4096 * 48 * 2;  // 50.3 MB
  float* part   = (float*)w;    w += (size_t)8 * 128 * 2304 * 4;   // 9.4 MB
  float* attn   = (float*)w;    w += (size_t)128 * 2304 * 4;       // 1.2 MB
  uint16_t* ao  = xb;  // x_bf16 is dead after gemm_qkv; alias to save workspace

  cast_x_kernel<<<24576, 256, 0, stream>>>(x, xb, 6291456);
  transpose_cast_kernel<<<6912, 256, 0, stream>>>(w_qkv, wqT, 768, 2304);
  transpose_cast_kernel<<<2304, 256, 0, stream>>>(w_proj, wpT, 768, 768);
  gemm256_kernel<0><<<1152, 512, 0, stream>>>(xb, wqT, b_qkv, Qt, Kt, Vb, nullptr);
  logits_mfma_kernel<<<dim3(128, 8), 256, 0, stream>>>(Qt, Kt, part);
  softmax_kernel<<<128, 256, 0, stream>>>(part, attn);
  blockdiag_kernel<<<dim3(128, 32), 256, 0, stream>>>(Vb, attn, ao);
  gemm256_kernel<1><<<384, 512, 0, stream>>>(ao, wpT, b_proj, nullptr, nullptr, nullptr, out);
}

// Round 7
// 402.468 us; speedup vs baseline: 2.7103x; 2.7103x over previous
//
#include <hip/hip_runtime.h>
#include <stdint.h>

// Problem constants: B=8, N=4096, C=768, G=16, D=48
// qkv GEMM: M=32768, N=2304, K=768 ; proj GEMM: M=32768, N=768, K=768
//
// Hard-won toolchain facts (rounds 3-6): 512-thread blocks get VGPR capped at
// exactly 128 (= 65536/512) under every launch-bounds spelling -> acc[8][4]
// spills to scratch (2.8 GB). 256-thread blocks allocate freely (236 VGPR seen,
// zero spill). So: 4-wave blocks only; keep per-wave acc <= [4][4] and LDS <= 48 KiB
// so 3 blocks/CU stay resident (round-5's 72 KiB ring -> 1 block/CU -> pipeline starved).

using short8 = __attribute__((__ext_vector_type__(8))) short;
using f32x4  = __attribute__((__ext_vector_type__(4))) float;

typedef const void __attribute__((address_space(1))) gv_t;
typedef void __attribute__((address_space(3))) lv_t;

__device__ __forceinline__ void gll16(const void* g, void* l) {
  __builtin_amdgcn_global_load_lds((gv_t*)g, (lv_t*)l, 16, 0, 0);
}

__device__ __forceinline__ uint16_t f2b(float f) {
  uint32_t x = __float_as_uint(f);
  uint32_t r = (x + 0x7fffu + ((x >> 16) & 1u)) >> 16;  // RNE
  return (uint16_t)r;
}
__device__ __forceinline__ float b2f(uint16_t u) {
  return __uint_as_float(((uint32_t)u) << 16);
}

// ---------------- cast / transpose helpers ----------------

__global__ __launch_bounds__(256) void cast_x_kernel(const float* __restrict__ x,
                                                     uint16_t* __restrict__ xb, int n4) {
  int i = blockIdx.x * 256 + threadIdx.x;
  if (i >= n4) return;
  f32x4 v = ((const f32x4*)x)[i];
  union { uint16_t u[4]; uint64_t q; } o;
  o.u[0] = f2b(v[0]); o.u[1] = f2b(v[1]); o.u[2] = f2b(v[2]); o.u[3] = f2b(v[3]);
  ((uint64_t*)xb)[i] = o.q;
}

// wt[n*K + k] = (bf16) w[k*N + n]
__global__ __launch_bounds__(256) void transpose_cast_kernel(const float* __restrict__ w,
                                                             uint16_t* __restrict__ wt,
                                                             int K, int N) {
  int i = blockIdx.x * 256 + threadIdx.x;
  if (i >= N * K) return;
  int n = i / K, k = i - n * K;
  wt[i] = f2b(w[(size_t)k * N + n]);
}

// ---------------- pipelined 128x128 GEMM, BK=32, ring-3 LDS (48 KiB), depth-2 ------
// A [M][768] bf16 row-major; Bt [N][768] bf16 row-major (weights transposed).
// 256 threads / 4 waves (2M x 2N), wave tile 64x64, acc[4][4] (64 VGPR).
// Counted vmcnt(4): 8 loads in flight (2 stages x 4/wave), drained only at tail.
// LDS swizzle (both sides): phys 16B-chunk = logical ^ ((row>>1)&3) -> 2-way banks = free.
// MODE 0: qkv epilogue (Q/K transposed via operand swap, V normal); MODE 1: proj f32 out.

template<int MODE>
__global__ __launch_bounds__(256) void gemm_ring_kernel(
    const uint16_t* __restrict__ A, const uint16_t* __restrict__ Bt,
    const float* __restrict__ bias,
    uint16_t* __restrict__ Qb, uint16_t* __restrict__ Kb,
    uint16_t* __restrict__ Vb, float* __restrict__ outf) {
  constexpr int NT = 24;                       // 768 / 32
  constexpr int NB = (MODE == 0) ? 18 : 6;     // 128-col blocks
  constexpr int NWG = 256 * NB;                // 256 row-blocks of 128
  constexpr int CPX = NWG / 8;
  // slot: A[128][32] (8192 elems? no: 4096) + B[128][32] -> 8192 elems = 16 KiB; ring-3.
  __shared__ uint16_t lds[3 * 8192];

  const int tid  = threadIdx.x;
  const int lane = tid & 63, w = tid >> 6;
  const int wm = w >> 1, wn = w & 1;
  const int lrow = lane & 15, kb = lane >> 4;

  int wg = (int)blockIdx.x;
  wg = (wg & 7) * CPX + (wg >> 3);             // bijective XCD swizzle (NWG%8==0)
  const int mblk = wg / NB, nblk = wg % NB;    // nblk fastest: A-panel L2 reuse
  const int m0 = mblk * 128, n0 = nblk * 128;
  const bool sw = (MODE == 0) && (n0 < 1536);  // Q/K blocks: swapped-operand MFMA

  // staging: wave w covers A rows [w*32,+32) and B rows ditto; lane l -> row (l>>2),
  // global 16B-chunk = (l&3)^((l>>3)&3) (inverse swizzle; linear LDS + swz read = id).
  const int grow  = lane >> 2;
  const int gslot = ((lane & 3) ^ ((lane >> 3) & 3)) << 3;
  const size_t arow0 = (size_t)(m0 + w * 32 + grow) * 768 + gslot;
  const size_t brow0 = (size_t)(n0 + w * 32 + grow) * 768 + gslot;

  auto stage = [&](int ts, int sl) {
    const size_t ko = (size_t)ts * 32;
    uint16_t* la = lds + sl * 8192 + w * 1024;          // wave-uniform LDS dests
    uint16_t* lb = lds + sl * 8192 + 4096 + w * 1024;
    gll16(A  + arow0 + ko,            la);
    gll16(A  + arow0 + ko + 16 * 768, la + 512);
    gll16(Bt + brow0 + ko,            lb);
    gll16(Bt + brow0 + ko + 16 * 768, lb + 512);
  };

  const int xslot = (kb ^ ((lrow >> 1) & 3)) << 3;  // swizzled read chunk (elements)

  f32x4 acc[4][4] = {};

  stage(0, 0); stage(1, 1);
  asm volatile("s_waitcnt vmcnt(4)" ::: "memory");
  __builtin_amdgcn_s_barrier();
  __builtin_amdgcn_sched_barrier(0);

  int sl = 0;
  for (int t = 0; t < NT; ++t) {
    const int sl2 = (sl >= 1) ? sl - 1 : 2;    // (t+2)%3
    if (t + 2 < NT) stage(t + 2, sl2);
    const uint16_t* sa = lds + sl * 8192;
    const uint16_t* sb = sa + 4096;
    short8 av[4], bv4[4];
#pragma unroll
    for (int mf = 0; mf < 4; ++mf)
      av[mf] = *(const short8*)(sa + (wm * 64 + mf * 16 + lrow) * 32 + xslot);
#pragma unroll
    for (int nf = 0; nf < 4; ++nf)
      bv4[nf] = *(const short8*)(sb + (wn * 64 + nf * 16 + lrow) * 32 + xslot);
    __builtin_amdgcn_s_setprio(1);
    if (sw) {
#pragma unroll
      for (int mf = 0; mf < 4; ++mf)
#pragma unroll
        for (int nf = 0; nf < 4; ++nf)
          acc[mf][nf] = __builtin_amdgcn_mfma_f32_16x16x32_bf16(bv4[nf], av[mf], acc[mf][nf], 0, 0, 0);
    } else {
#pragma unroll
      for (int mf = 0; mf < 4; ++mf)
#pragma unroll
        for (int nf = 0; nf < 4; ++nf)
          acc[mf][nf] = __builtin_amdgcn_mfma_f32_16x16x32_bf16(av[mf], bv4[nf], acc[mf][nf], 0, 0, 0);
    }
    __builtin_amdgcn_s_setprio(0);
    if (t < NT - 1) {
      if (t < NT - 2) asm volatile("s_waitcnt vmcnt(4)" ::: "memory");
      else            asm volatile("s_waitcnt vmcnt(0)" ::: "memory");
      __builtin_amdgcn_s_barrier();
      __builtin_amdgcn_sched_barrier(0);
    }
    sl = (sl == 2) ? 0 : sl + 1;
  }

  const float qscale = 0.015625f;  // 4096^-0.5
  if (MODE == 0) {
    const int which = n0 / 768;
    if (which < 2) {
      // swapped-operand MFMA -> frag col (lrow) = token, frag row (kb*4+r) = channel
      uint16_t* dst = (which == 0) ? Qb : Kb;
      const float sc = (which == 0) ? qscale : 1.0f;
#pragma unroll
      for (int mf = 0; mf < 4; ++mf) {
        const int token = m0 + wm * 64 + mf * 16 + lrow;
        const int b = token >> 12, nn = token & 4095;
#pragma unroll
        for (int nf = 0; nf < 4; ++nf) {
          const int colb = n0 + wn * 64 + nf * 16 + kb * 4;
#pragma unroll
          for (int r = 0; r < 4; ++r) {
            const int chan = colb + r - which * 768;
            const int g = chan / 48, d = chan - g * 48;
            dst[(((size_t)b * 16 + g) * 48 + d) * 4096 + nn] =
                f2b((acc[mf][nf][r] + bias[colb + r]) * sc);
          }
        }
      }
    } else {
#pragma unroll
      for (int mf = 0; mf < 4; ++mf) {
        const int rowb = m0 + wm * 64 + mf * 16 + kb * 4;
#pragma unroll
        for (int nf = 0; nf < 4; ++nf) {
          const int col = n0 + wn * 64 + nf * 16 + lrow;
          const int c = col - 1536, g = c / 48, d = c - g * 48;
          const float bb = bias[col];
#pragma unroll
          for (int r = 0; r < 4; ++r) {
            const int row = rowb + r;
            const int b = row >> 12, nn = row & 4095;
            Vb[(((size_t)b * 16 + g) * 4096 + nn) * 48 + d] = f2b(acc[mf][nf][r] + bb);
          }
        }
      }
    }
  } else {
#pragma unroll
    for (int mf = 0; mf < 4; ++mf) {
      const int rowb = m0 + wm * 64 + mf * 16 + kb * 4;
#pragma unroll
      for (int nf = 0; nf < 4; ++nf) {
        const int col = n0 + wn * 64 + nf * 16 + lrow;
        const float bb = bias[col];
#pragma unroll
        for (int r = 0; r < 4; ++r)
          outf[(size_t)(rowb + r) * 768 + col] = acc[mf][nf][r] + bb;
      }
    }
  }
}

// ---------------- logits via MFMA over token-K ----------------
// Qt,Kt: [bg][48][4096] bf16.  part[ch][bg][48][48] f32, ch in 0..7 (512 tokens each)

__global__ __launch_bounds__(256) void logits_mfma_kernel(
    const uint16_t* __restrict__ Qt, const uint16_t* __restrict__ Kt,
    float* __restrict__ part) {
  const int bg = blockIdx.x;     // 0..127
  const int ch = blockIdx.y;     // 0..7
  const int tid = threadIdx.x;
  const int lane = tid & 63, w = tid >> 6;
  const int lrow = lane & 15, kb = lane >> 4;

  const size_t qbase = (size_t)bg * 48 * 4096;
  const int tok0 = ch * 512 + w * 128;

  f32x4 acc[3][3] = {};
#pragma unroll
  for (int s = 0; s < 4; ++s) {
    const int tok = tok0 + s * 32 + kb * 8;
    short8 av[3], bvv[3];
#pragma unroll
    for (int dm = 0; dm < 3; ++dm) {
      av[dm]  = *(const short8*)(Qt + qbase + (size_t)(dm * 16 + lrow) * 4096 + tok);
      bvv[dm] = *(const short8*)(Kt + qbase + (size_t)(dm * 16 + lrow) * 4096 + tok);
    }
#pragma unroll
    for (int dm = 0; dm < 3; ++dm)
#pragma unroll
      for (int em = 0; em < 3; ++em)
        acc[dm][em] = __builtin_amdgcn_mfma_f32_16x16x32_bf16(av[dm], bvv[em], acc[dm][em], 0, 0, 0);
  }

  __shared__ float red[4][2304];
#pragma unroll
  for (int dm = 0; dm < 3; ++dm)
#pragma unroll
    for (int em = 0; em < 3; ++em)
#pragma unroll
      for (int r = 0; r < 4; ++r) {
        const int d = dm * 16 + kb * 4 + r;
        const int e = em * 16 + lrow;
        red[w][d * 48 + e] = acc[dm][em][r];
      }
  __syncthreads();
  float* dst = part + ((size_t)ch * 128 + bg) * 2304;
  for (int i = tid; i < 2304; i += 256)
    dst[i] = red[0][i] + red[1][i] + red[2][i] + red[3][i];
}

// ---------------- reduce partials + softmax over e ----------------

__global__ __launch_bounds__(256) void softmax_kernel(const float* __restrict__ part,
                                                      float* __restrict__ attn) {
  const int bg = blockIdx.x;
  const int tid = threadIdx.x;
  __shared__ float l[2304];
  for (int p = tid; p < 2304; p += 256) {
    float s = 0.f;
    for (int chk = 0; chk < 8; ++chk) s += part[((size_t)chk * 128 + bg) * 2304 + p];
    l[p] = s;
  }
  __syncthreads();
  if (tid < 48) {
    const int d = tid;
    float m = -1e30f;
    for (int e = 0; e < 48; ++e) m = fmaxf(m, l[d * 48 + e]);
    float s = 0.f;
    for (int e = 0; e < 48; ++e) s += expf(l[d * 48 + e] - m);
    const float inv = 1.0f / s;
    for (int e = 0; e < 48; ++e)
      attn[(size_t)bg * 2304 + d * 48 + e] = expf(l[d * 48 + e] - m) * inv;
  }
}

// ---------------- block-diag: ao[b][n][g*48+d] = sum_e attn[bg][d][e] * v[bg][n][e] ------

__global__ __launch_bounds__(256) void blockdiag_kernel(const uint16_t* __restrict__ Vb,
                                                        const float* __restrict__ attn,
                                                        uint16_t* __restrict__ ao) {
  const int bg = blockIdx.x, ch = blockIdx.y;
  const int b = bg >> 4, g = bg & 15;
  const int tid = threadIdx.x;
  __shared__ uint16_t vs[128 * 64];
  __shared__ uint16_t as2[48 * 64];
  const size_t vbase = ((size_t)bg * 4096 + (size_t)ch * 128) * 48;
  // vectorized V staging: 128 rows x 6 uint4-chunks (48 bf16 = 6 x 8)
  const uint4* vg = (const uint4*)(Vb + vbase);
  for (int u = tid; u < 768; u += 256) {
    const int n = u / 6, c = u - n * 6;
    *(uint4*)(vs + n * 64 + c * 8) = vg[u];
  }
  {  // zero the 16-col pad (cols 48..63), 128 rows x 2 chunks = 256 units
    const int n = tid >> 1, c = 6 + (tid & 1);
    uint4 z; z.x = z.y = z.z = z.w = 0u;
    *(uint4*)(vs + n * 64 + c * 8) = z;
  }
  const float* ab = attn + (size_t)bg * 2304;
  for (int i = tid; i < 48 * 64; i += 256) {
    int d = i >> 6, e = i & 63;
    as2[i] = (e < 48) ? f2b(ab[d * 48 + e]) : (uint16_t)0;
  }
  __syncthreads();
  const int lane = tid & 63, w = tid >> 6;
  const int lrow = lane & 15, kb = lane >> 4;
  f32x4 acc[2][3] = {};
#pragma unroll
  for (int ksb = 0; ksb < 2; ++ksb) {
    short8 a[2], bb[3];
#pragma unroll
    for (int i = 0; i < 2; ++i)
      a[i] = *(const short8*)(vs + (w * 32 + i * 16 + lrow) * 64 + ksb * 32 + kb * 8);
#pragma unroll
    for (int c = 0; c < 3; ++c)
      bb[c] = *(const short8*)(as2 + (c * 16 + lrow) * 64 + ksb * 32 + kb * 8);
#pragma unroll
    for (int i = 0; i < 2; ++i)
#pragma unroll
      for (int c = 0; c < 3; ++c)
        acc[i][c] = __builtin_amdgcn_mfma_f32_16x16x32_bf16(a[i], bb[c], acc[i][c], 0, 0, 0);
  }
#pragma unroll
  for (int i = 0; i < 2; ++i)
#pragma unroll
    for (int c = 0; c < 3; ++c)
#pragma unroll
      for (int r = 0; r < 4; ++r) {
        const int nl = w * 32 + i * 16 + kb * 4 + r;
        const int dcol = c * 16 + lrow;
        const size_t row = (size_t)b * 4096 + (size_t)ch * 128 + nl;
        ao[row * 768 + g * 48 + dcol] = f2b(acc[i][c][r]);
      }
}

// ---------------- launcher ----------------

extern "C" void kernel_launch(void* const* d_in, const int* in_sizes, int n_in,
                              void* d_out, int out_size, void* d_ws, size_t ws_size,
                              hipStream_t stream) {
  const float* x      = (const float*)d_in[0];
  const float* w_qkv  = (const float*)d_in[1];
  const float* b_qkv  = (const float*)d_in[2];
  const float* w_proj = (const float*)d_in[3];
  const float* b_proj = (const float*)d_in[4];
  float* out = (float*)d_out;

  char* w = (char*)d_ws;
  uint16_t* xb  = (uint16_t*)w; w += (size_t)32768 * 768 * 2;      // 50.3 MB (reused as ao)
  uint16_t* wqT = (uint16_t*)w; w += (size_t)2304 * 768 * 2;       // 3.5 MB
  uint16_t* wpT = (uint16_t*)w; w += (size_t)768 * 768 * 2;        // 1.2 MB
  uint16_t* Qt  = (uint16_t*)w; w += (size_t)128 * 48 * 4096 * 2;  // 50.3 MB
  uint16_t* Kt  = (uint16_t*)w; w += (size_t)128 * 48 * 4096 * 2;  // 50.3 MB
  uint16_t* Vb  = (uint16_t*)w; w += (size_t)128 * 4096 * 48 * 2;  // 50.3 MB
  float* part   = (float*)w;    w += (size_t)8 * 128 * 2304 * 4;   // 9.4 MB
  float* attn   = (float*)w;    w += (size_t)128 * 2304 * 4;       // 1.2 MB
  uint16_t* ao  = xb;  // x_bf16 is dead after gemm_qkv; alias to save workspace

  cast_x_kernel<<<24576, 256, 0, stream>>>(x, xb, 6291456);
  transpose_cast_kernel<<<6912, 256, 0, stream>>>(w_qkv, wqT, 768, 2304);
  transpose_cast_kernel<<<2304, 256, 0, stream>>>(w_proj, wpT, 768, 768);
  gemm_ring_kernel<0><<<4608, 256, 0, stream>>>(xb, wqT, b_qkv, Qt, Kt, Vb, nullptr);
  logits_mfma_kernel<<<dim3(128, 8), 256, 0, stream>>>(Qt, Kt, part);
  softmax_kernel<<<128, 256, 0, stream>>>(part, attn);
  blockdiag_kernel<<<dim3(128, 32), 256, 0, stream>>>(Vb, attn, ao);
  gemm_ring_kernel<1><<<1536, 256, 0, stream>>>(ao, wpT, b_proj, nullptr, nullptr, nullptr, out);
}